// Round 3
// baseline (60.662 us; speedup 1.0000x reference)
//
#include <hip/hip_runtime.h>

namespace {

constexpr int kNB = 256;   // batch
constexpr int kNQ = 16;    // queries per batch
constexpr int kNK = 200;   // keys per batch
constexpr int kDK = 64;    // key/query feature size
constexpr int kNH = 128;   // hidden
constexpr int kThreads = 1024;  // 16 waves
constexpr int kS = 132;         // kh row stride in floats
constexpr float kNeg = -1000000000.0f;
constexpr float kC2 = 2.8853900817779268f;  // 2*log2(e): exp(2x)=exp2(kC2*x)

constexpr int kKhFloats = kNK * kS;   // 26400 floats = 105600 B
constexpr int kScFloats = kNQ * kNK;  // 3200 floats  = 12800 B
constexpr size_t kSmemBytes = (size_t)(kKhFloats + kScFloats) * sizeof(float);  // 118400

__device__ __forceinline__ float exp2_hw(float x) {
#if defined(__has_builtin)
# if __has_builtin(__builtin_amdgcn_exp2f)
  return __builtin_amdgcn_exp2f(x);
# else
  return __expf(x * 0.69314718055994531f);
# endif
#else
  return __expf(x * 0.69314718055994531f);
#endif
}

template <int CTRL>
__device__ __forceinline__ float dpp_add(float v) {
  int sw = __builtin_amdgcn_update_dpp(0, __float_as_int(v), CTRL, 0xF, 0xF, true);
  return v + __int_as_float(sw);
}

// 16 waves, 4 waves/SIMD -> 128-VGPR budget: wcol[64] stays register-resident.
__launch_bounds__(kThreads, 4)
__global__ void bahdanau_fused(const float* __restrict__ queries,
                               const float* __restrict__ keys,
                               const float* __restrict__ masks,
                               const float* __restrict__ Wq,
                               const float* __restrict__ bq,
                               const float* __restrict__ Wk,
                               const float* __restrict__ bk,
                               const float* __restrict__ Wv,
                               float* __restrict__ out_attn,
                               float* __restrict__ out_w) {
  extern __shared__ __align__(16) float smem[];
  float* skh = smem;              // [200][132] kh'  (later: epilogue partials)
  float* ssc = smem + kKhFloats;  // [16][200]  (qh' staging -> scores -> weights)

  const int tid  = threadIdx.x;
  const int b    = blockIdx.x;
  const int lane = tid & 63;
  const int wave = __builtin_amdgcn_readfirstlane(tid >> 6);   // 0..15
  const int j    = lane & 15;   // h-slice (8 h each)
  const int q16  = lane >> 4;   // k offset within iteration
  const int hbase = 8 * j;
  const int h    = tid & (kNH - 1);
  const int kgrp = __builtin_amdgcn_readfirstlane(tid >> 7);   // 0..7

  const float* kb = keys + (size_t)b * kNK * kDK;

  float wcol[kDK];

  // ---- qh' = kC2*(queries @ Wq + bq) staged into ssc as [16][128] ----
  {
#pragma unroll
    for (int d = 0; d < kDK; ++d) wcol[d] = Wq[d * kNH + h];
    const float bqh = bq[h];
    const float* qb = queries + (size_t)b * kNQ * kDK;
    const float* r0 = qb + (size_t)kgrp * kDK;          // wave-uniform rows
    const float* r1 = qb + (size_t)(kgrp + 8) * kDK;
    float a0 = bqh, a1 = bqh;
#pragma unroll
    for (int d = 0; d < kDK; ++d) {
      a0 = fmaf(r0[d], wcol[d], a0);
      a1 = fmaf(r1[d], wcol[d], a1);
    }
    ssc[kgrp * kNH + h]       = kC2 * a0;
    ssc[(kgrp + 8) * kNH + h] = kC2 * a1;
  }

  // ---- switch wcol to Wk column; per-lane Wv slice ----
#pragma unroll
  for (int d = 0; d < kDK; ++d) wcol[d] = Wk[d * kNH + h];
  const float bkh = bk[h];
  float wv2[8];
#pragma unroll
  for (int m = 0; m < 8; ++m) wv2[m] = -2.0f * Wv[hbase + m];

  __syncthreads();  // qh' visible

  // per-lane qh' slices: wave (qg,kg) handles queries 4qg..4qg+3, k-group kg
  const int qg = wave >> 2;
  const int kg = wave & 3;
  float qreg[4][8];
#pragma unroll
  for (int qi = 0; qi < 4; ++qi) {
    const float4 qa = *reinterpret_cast<const float4*>(&ssc[(4 * qg + qi) * kNH + hbase]);
    const float4 qb4 = *reinterpret_cast<const float4*>(&ssc[(4 * qg + qi) * kNH + hbase + 4]);
    qreg[qi][0] = qa.x;  qreg[qi][1] = qa.y;  qreg[qi][2] = qa.z;  qreg[qi][3] = qa.w;
    qreg[qi][4] = qb4.x; qreg[qi][5] = qb4.y; qreg[qi][6] = qb4.z; qreg[qi][7] = qb4.w;
  }

  // ---- kh' projection: group kgrp -> rows [25*kgrp, +25), all 200 rows in LDS ----
  {
    const int rbase = 25 * kgrp;
    for (int u = 0; u < 12; ++u) {
      const int r = rbase + 2 * u;
      const float* ra = kb + (size_t)r * kDK;  // wave-uniform -> s_load
      float a0 = bkh, a1 = bkh;
#pragma unroll
      for (int d = 0; d < kDK; ++d) {
        a0 = fmaf(ra[d], wcol[d], a0);
        a1 = fmaf(ra[kDK + d], wcol[d], a1);
      }
      skh[(size_t)r * kS + h]       = kC2 * a0;
      skh[(size_t)(r + 1) * kS + h] = kC2 * a1;
    }
    const int r = rbase + 24;
    const float* ra = kb + (size_t)r * kDK;
    float a0 = bkh;
#pragma unroll
    for (int d = 0; d < kDK; ++d) a0 = fmaf(ra[d], wcol[d], a0);
    skh[(size_t)r * kS + h] = kC2 * a0;
  }

  __syncthreads();  // kh' visible; all qreg reads done -> ssc reusable for scores

  // ---- score: one kh read feeds 4 queries; k = 16i + 4kg + q16 ----
  {
    auto score_k = [&](int k) {
      const float* krow = &skh[(size_t)k * kS + hbase];
      const float4 ka  = *reinterpret_cast<const float4*>(krow);
      const float4 kb4 = *reinterpret_cast<const float4*>(krow + 4);
#pragma unroll
      for (int qi = 0; qi < 4; ++qi) {
        const float e0 = exp2_hw(qreg[qi][0] + ka.x);
        const float e1 = exp2_hw(qreg[qi][1] + ka.y);
        const float e2 = exp2_hw(qreg[qi][2] + ka.z);
        const float e3 = exp2_hw(qreg[qi][3] + ka.w);
        const float e4 = exp2_hw(qreg[qi][4] + kb4.x);
        const float e5 = exp2_hw(qreg[qi][5] + kb4.y);
        const float e6 = exp2_hw(qreg[qi][6] + kb4.z);
        const float e7 = exp2_hw(qreg[qi][7] + kb4.w);
        const float r0 = __builtin_amdgcn_rcpf(1.0f + e0);
        const float r1 = __builtin_amdgcn_rcpf(1.0f + e1);
        const float r2 = __builtin_amdgcn_rcpf(1.0f + e2);
        const float r3 = __builtin_amdgcn_rcpf(1.0f + e3);
        const float r4 = __builtin_amdgcn_rcpf(1.0f + e4);
        const float r5 = __builtin_amdgcn_rcpf(1.0f + e5);
        const float r6 = __builtin_amdgcn_rcpf(1.0f + e6);
        const float r7 = __builtin_amdgcn_rcpf(1.0f + e7);
        float acc0 = wv2[0] * r0;
        acc0 = fmaf(wv2[1], r1, acc0);
        acc0 = fmaf(wv2[2], r2, acc0);
        acc0 = fmaf(wv2[3], r3, acc0);
        float acc1 = wv2[4] * r4;
        acc1 = fmaf(wv2[5], r5, acc1);
        acc1 = fmaf(wv2[6], r6, acc1);
        acc1 = fmaf(wv2[7], r7, acc1);
        float acc = acc0 + acc1;
        acc = dpp_add<0xB1>(acc);   // xor 1
        acc = dpp_add<0x4E>(acc);   // xor 2
        acc = dpp_add<0x141>(acc);  // row_half_mirror
        acc = dpp_add<0x140>(acc);  // row_mirror
        if (j == 0) ssc[(4 * qg + qi) * kNK + k] = acc;
      }
    };
    for (int i = 0; i < 12; ++i) score_k(16 * i + 4 * kg + q16);
    if (kg < 2) score_k(192 + 4 * kg + q16);  // tail k=192..199
  }

  // ---- mask prefetch (hides HBM latency under the barrier drain) ----
  const float* mrow = masks + ((size_t)b * kNQ + wave) * kNK;
  const bool tail = lane < (kNK - 192);
  const float mm0 = mrow[lane];
  const float mm1 = mrow[lane + 64];
  const float mm2 = mrow[lane + 128];
  const float mm3 = tail ? mrow[lane + 192] : 0.0f;

  __syncthreads();  // scores visible

  // ---- softmax over k (wave w owns query row w) ----
  {
    const float* sr = &ssc[wave * kNK];
    float v0 = fmaf(mm0, kNeg, sr[lane]);
    float v1 = fmaf(mm1, kNeg, sr[lane + 64]);
    float v2 = fmaf(mm2, kNeg, sr[lane + 128]);
    float v3 = tail ? fmaf(mm3, kNeg, sr[lane + 192]) : -1e30f;
    float m = fmaxf(fmaxf(v0, v1), fmaxf(v2, v3));
#pragma unroll
    for (int off = 32; off > 0; off >>= 1) m = fmaxf(m, __shfl_xor(m, off, 64));
    const float e0 = __expf(v0 - m);
    const float e1 = __expf(v1 - m);
    const float e2 = __expf(v2 - m);
    const float e3 = tail ? __expf(v3 - m) : 0.f;
    float sum = (e0 + e1) + (e2 + e3);
#pragma unroll
    for (int off = 32; off > 0; off >>= 1) sum += __shfl_xor(sum, off, 64);
    const float rs = __builtin_amdgcn_rcpf(sum);
    float* og = out_w + ((size_t)b * kNQ + wave) * kNK;
    float* sw = &ssc[wave * kNK];
    const float w0 = e0 * rs, w1 = e1 * rs, w2 = e2 * rs, w3 = e3 * rs;
    sw[lane]       = w0;  og[lane]       = w0;
    sw[lane + 64]  = w1;  og[lane + 64]  = w1;
    sw[lane + 128] = w2;  og[lane + 128] = w2;
    if (tail) { sw[lane + 192] = w3; og[lane + 192] = w3; }
  }
  __syncthreads();  // weights visible; skh now dead -> reuse for partials

  // ---- epilogue: wave (qg,kg) does partial GEMV over its k-range ----
  {
    float* pk = skh;  // [16][4][64] partials
    const int kstart = 52 * kg;
    const int kend = (kg == 3) ? kNK : (kstart + 52);
    const float* kb2 = kb + lane;  // d = lane
    float acc[4] = {0.f, 0.f, 0.f, 0.f};
    for (int k0 = kstart; k0 < kend; k0 += 4) {
      const float kv0 = kb2[(size_t)(k0 + 0) * kDK];
      const float kv1 = kb2[(size_t)(k0 + 1) * kDK];
      const float kv2 = kb2[(size_t)(k0 + 2) * kDK];
      const float kv3 = kb2[(size_t)(k0 + 3) * kDK];
#pragma unroll
      for (int qi = 0; qi < 4; ++qi) {
        const float4 wq = *reinterpret_cast<const float4*>(&ssc[(4 * qg + qi) * kNK + k0]);
        acc[qi] = fmaf(wq.x, kv0, acc[qi]);
        acc[qi] = fmaf(wq.y, kv1, acc[qi]);
        acc[qi] = fmaf(wq.z, kv2, acc[qi]);
        acc[qi] = fmaf(wq.w, kv3, acc[qi]);
      }
    }
#pragma unroll
    for (int qi = 0; qi < 4; ++qi)
      pk[((4 * qg + qi) * 4 + kg) * kDK + lane] = acc[qi];
  }
  __syncthreads();

  // ---- final combine: wave w sums 4 partials of query w ----
  {
    const float* pk = skh;
    const float r = pk[(wave * 4 + 0) * kDK + lane] + pk[(wave * 4 + 1) * kDK + lane] +
                    pk[(wave * 4 + 2) * kDK + lane] + pk[(wave * 4 + 3) * kDK + lane];
    out_attn[((size_t)b * kNQ + wave) * kDK + lane] = r;
  }
}

}  // namespace

extern "C" void kernel_launch(void* const* d_in, const int* in_sizes, int n_in,
                              void* d_out, int out_size, void* d_ws, size_t ws_size,
                              hipStream_t stream) {
  const float* queries = (const float*)d_in[0];
  const float* keys    = (const float*)d_in[1];
  const float* masks   = (const float*)d_in[2];
  // d_in[3] = num_neg (unused)
  const float* Wq = (const float*)d_in[4];
  const float* bq = (const float*)d_in[5];
  const float* Wk = (const float*)d_in[6];
  const float* bk = (const float*)d_in[7];
  const float* Wv = (const float*)d_in[8];
  // d_in[9] = bv: softmax-invariant, dropped

  float* out_attn = (float*)d_out;                       // (B, NQ, 64)
  float* out_w    = out_attn + (size_t)kNB * kNQ * kDK;  // (B, NQ, 200, 1)

  // opt-in to >64KB dynamic LDS (gfx950: up to 160KB/workgroup). Host-side,
  // idempotent, not a stream op -> graph-capture safe.
  hipFuncSetAttribute((const void*)bahdanau_fused,
                      hipFuncAttributeMaxDynamicSharedMemorySize, (int)kSmemBytes);

  bahdanau_fused<<<kNB, kThreads, kSmemBytes, stream>>>(queries, keys, masks, Wq, bq,
                                                        Wk, bk, Wv, out_attn, out_w);
}

// Round 4
// 51.790 us; speedup vs baseline: 1.1713x; 1.1713x over previous
//
#include <hip/hip_runtime.h>

namespace {

constexpr int kNB = 256;   // batch
constexpr int kNQ = 16;    // queries per batch
constexpr int kNK = 200;   // keys per batch
constexpr int kDK = 64;    // key/query feature size
constexpr int kNH = 128;   // hidden
constexpr int kThreads = 1024;  // 16 waves
constexpr int kS = 132;         // kh row stride in floats
constexpr float kNeg = -1000000000.0f;
constexpr float kC2 = 2.8853900817779268f;  // 2*log2(e): exp(2x)=exp2(kC2*x)

constexpr int kKhFloats = kNK * kS;   // 26400 floats = 105600 B
constexpr int kScFloats = kNQ * kNK;  // 3200 floats  = 12800 B
constexpr int kQhFloats = kNQ * kNH;  // 2048 floats  = 8192 B
constexpr size_t kSmemBytes =
    (size_t)(kKhFloats + kScFloats + kQhFloats) * sizeof(float);  // 126592 B

__device__ __forceinline__ float exp2_hw(float x) {
#if defined(__has_builtin)
# if __has_builtin(__builtin_amdgcn_exp2f)
  return __builtin_amdgcn_exp2f(x);
# else
  return __expf(x * 0.69314718055994531f);
# endif
#else
  return __expf(x * 0.69314718055994531f);
#endif
}

template <int CTRL>
__device__ __forceinline__ float dpp_add(float v) {
  int sw = __builtin_amdgcn_update_dpp(0, __float_as_int(v), CTRL, 0xF, 0xF, true);
  return v + __int_as_float(sw);
}

// 16 waves = 4 waves/SIMD (hard requirement for a 1024-thread block) -> <=128 VGPR.
__launch_bounds__(kThreads, 4)
__global__ void bahdanau_fused(const float* __restrict__ queries,
                               const float* __restrict__ keys,
                               const float* __restrict__ masks,
                               const float* __restrict__ Wq,
                               const float* __restrict__ bq,
                               const float* __restrict__ Wk,
                               const float* __restrict__ bk,
                               const float* __restrict__ Wv,
                               float* __restrict__ out_attn,
                               float* __restrict__ out_w) {
  extern __shared__ __align__(16) float smem[];
  float* skh = smem;                           // [200][132] kh' (later: partials)
  float* ssc = smem + kKhFloats;               // [16][200] scores -> weights
  float* sqh = smem + kKhFloats + kScFloats;   // [16][128] qh'

  const int tid  = threadIdx.x;
  const int b    = blockIdx.x;
  const int lane = tid & 63;
  const int wave = __builtin_amdgcn_readfirstlane(tid >> 6);   // 0..15
  const int j    = lane & 15;   // h-slice (8 h each)
  const int q16  = lane >> 4;   // k offset within iteration
  const int hbase = 8 * j;
  const int h    = tid & (kNH - 1);
  const int kgrp = __builtin_amdgcn_readfirstlane(tid >> 7);   // 0..7

  const float* kb = keys + (size_t)b * kNK * kDK;

  float wcol[kDK];

  // ---- qh' = kC2*(queries @ Wq + bq) -> sqh[16][128] ----
  {
#pragma unroll
    for (int d = 0; d < kDK; ++d) wcol[d] = Wq[d * kNH + h];
#pragma unroll
    for (int d = 0; d < kDK; ++d) asm volatile("" : "+v"(wcol[d]));  // pin: no remat
    const float bqh = bq[h];
    const float* qb = queries + (size_t)b * kNQ * kDK;
    const float* r0 = qb + (size_t)kgrp * kDK;          // wave-uniform rows
    const float* r1 = qb + (size_t)(kgrp + 8) * kDK;
    float a0 = bqh, a1 = bqh;
#pragma unroll
    for (int d = 0; d < kDK; ++d) {
      a0 = fmaf(r0[d], wcol[d], a0);
      a1 = fmaf(r1[d], wcol[d], a1);
    }
    sqh[kgrp * kNH + h]       = kC2 * a0;
    sqh[(kgrp + 8) * kNH + h] = kC2 * a1;
  }

  // ---- kh' projection: wcol = Wk column, pinned; rows [25*kgrp, +25) ----
  {
#pragma unroll
    for (int d = 0; d < kDK; ++d) wcol[d] = Wk[d * kNH + h];
#pragma unroll
    for (int d = 0; d < kDK; ++d) asm volatile("" : "+v"(wcol[d]));  // pin: no remat
    const float bkh = bk[h];
    const int rbase = 25 * kgrp;
    for (int u = 0; u < 12; ++u) {
      const int r = rbase + 2 * u;
      const float* ra = kb + (size_t)r * kDK;  // wave-uniform -> scalar loads
      float a0 = bkh, a1 = bkh;
#pragma unroll
      for (int d = 0; d < kDK; ++d) {
        a0 = fmaf(ra[d], wcol[d], a0);
        a1 = fmaf(ra[kDK + d], wcol[d], a1);
      }
      skh[(size_t)r * kS + h]       = kC2 * a0;
      skh[(size_t)(r + 1) * kS + h] = kC2 * a1;
    }
    const int r = rbase + 24;
    const float* ra = kb + (size_t)r * kDK;
    float a0 = bkh;
#pragma unroll
    for (int d = 0; d < kDK; ++d) a0 = fmaf(ra[d], wcol[d], a0);
    skh[(size_t)r * kS + h] = kC2 * a0;
  }

  // per-lane Wv slice (tiny, broadcast-friendly)
  float wv2[8];
  {
    const float4 wva = *reinterpret_cast<const float4*>(&Wv[hbase]);
    const float4 wvb = *reinterpret_cast<const float4*>(&Wv[hbase + 4]);
    wv2[0] = -2.0f * wva.x; wv2[1] = -2.0f * wva.y;
    wv2[2] = -2.0f * wva.z; wv2[3] = -2.0f * wva.w;
    wv2[4] = -2.0f * wvb.x; wv2[5] = -2.0f * wvb.y;
    wv2[6] = -2.0f * wvb.z; wv2[7] = -2.0f * wvb.w;
  }

  __syncthreads();  // qh' + kh' visible; wcol dead from here (pressure drops)

  // ---- per-lane qh' slices: wave (qg,kg) covers queries 4qg..4qg+3, k-group kg ----
  const int qg = wave >> 2;
  const int kg = wave & 3;
  float qreg[4][8];
#pragma unroll
  for (int qi = 0; qi < 4; ++qi) {
    const float4 qa  = *reinterpret_cast<const float4*>(&sqh[(4 * qg + qi) * kNH + hbase]);
    const float4 qb4 = *reinterpret_cast<const float4*>(&sqh[(4 * qg + qi) * kNH + hbase + 4]);
    qreg[qi][0] = qa.x;  qreg[qi][1] = qa.y;  qreg[qi][2] = qa.z;  qreg[qi][3] = qa.w;
    qreg[qi][4] = qb4.x; qreg[qi][5] = qb4.y; qreg[qi][6] = qb4.z; qreg[qi][7] = qb4.w;
  }

  // ---- score: one kh read feeds 4 queries; k = 16i + 4kg + q16 ----
  {
    auto score_k = [&](int k) {
      const float* krow = &skh[(size_t)k * kS + hbase];
      const float4 ka  = *reinterpret_cast<const float4*>(krow);
      const float4 kb4 = *reinterpret_cast<const float4*>(krow + 4);
#pragma unroll
      for (int qi = 0; qi < 4; ++qi) {
        const float e0 = exp2_hw(qreg[qi][0] + ka.x);
        const float e1 = exp2_hw(qreg[qi][1] + ka.y);
        const float e2 = exp2_hw(qreg[qi][2] + ka.z);
        const float e3 = exp2_hw(qreg[qi][3] + ka.w);
        const float e4 = exp2_hw(qreg[qi][4] + kb4.x);
        const float e5 = exp2_hw(qreg[qi][5] + kb4.y);
        const float e6 = exp2_hw(qreg[qi][6] + kb4.z);
        const float e7 = exp2_hw(qreg[qi][7] + kb4.w);
        const float r0 = __builtin_amdgcn_rcpf(1.0f + e0);
        const float r1 = __builtin_amdgcn_rcpf(1.0f + e1);
        const float r2 = __builtin_amdgcn_rcpf(1.0f + e2);
        const float r3 = __builtin_amdgcn_rcpf(1.0f + e3);
        const float r4 = __builtin_amdgcn_rcpf(1.0f + e4);
        const float r5 = __builtin_amdgcn_rcpf(1.0f + e5);
        const float r6 = __builtin_amdgcn_rcpf(1.0f + e6);
        const float r7 = __builtin_amdgcn_rcpf(1.0f + e7);
        float acc0 = wv2[0] * r0;
        acc0 = fmaf(wv2[1], r1, acc0);
        acc0 = fmaf(wv2[2], r2, acc0);
        acc0 = fmaf(wv2[3], r3, acc0);
        float acc1 = wv2[4] * r4;
        acc1 = fmaf(wv2[5], r5, acc1);
        acc1 = fmaf(wv2[6], r6, acc1);
        acc1 = fmaf(wv2[7], r7, acc1);
        float acc = acc0 + acc1;
        acc = dpp_add<0xB1>(acc);   // xor 1
        acc = dpp_add<0x4E>(acc);   // xor 2
        acc = dpp_add<0x141>(acc);  // row_half_mirror (8-fold)
        acc = dpp_add<0x140>(acc);  // row_mirror (16-fold)
        if (j == 0) ssc[(4 * qg + qi) * kNK + k] = acc;
      }
    };
    for (int i = 0; i < 12; ++i) score_k(16 * i + 4 * kg + q16);
    if (kg < 2) score_k(192 + 4 * kg + q16);  // tail k=192..199
  }

  // ---- mask prefetch (hides HBM latency under the barrier) ----
  const float* mrow = masks + ((size_t)b * kNQ + wave) * kNK;
  const bool tail = lane < (kNK - 192);
  const float mm0 = mrow[lane];
  const float mm1 = mrow[lane + 64];
  const float mm2 = mrow[lane + 128];
  const float mm3 = tail ? mrow[lane + 192] : 0.0f;

  __syncthreads();  // scores visible

  // ---- softmax over k (wave w owns query row w) ----
  {
    const float* sr = &ssc[wave * kNK];
    float v0 = fmaf(mm0, kNeg, sr[lane]);
    float v1 = fmaf(mm1, kNeg, sr[lane + 64]);
    float v2 = fmaf(mm2, kNeg, sr[lane + 128]);
    float v3 = tail ? fmaf(mm3, kNeg, sr[lane + 192]) : -1e30f;
    float m = fmaxf(fmaxf(v0, v1), fmaxf(v2, v3));
#pragma unroll
    for (int off = 32; off > 0; off >>= 1) m = fmaxf(m, __shfl_xor(m, off, 64));
    const float e0 = __expf(v0 - m);
    const float e1 = __expf(v1 - m);
    const float e2 = __expf(v2 - m);
    const float e3 = tail ? __expf(v3 - m) : 0.f;
    float sum = (e0 + e1) + (e2 + e3);
#pragma unroll
    for (int off = 32; off > 0; off >>= 1) sum += __shfl_xor(sum, off, 64);
    const float rs = __builtin_amdgcn_rcpf(sum);
    float* og = out_w + ((size_t)b * kNQ + wave) * kNK;
    float* sw = &ssc[wave * kNK];
    const float w0 = e0 * rs, w1 = e1 * rs, w2 = e2 * rs, w3 = e3 * rs;
    sw[lane]       = w0;  og[lane]       = w0;
    sw[lane + 64]  = w1;  og[lane + 64]  = w1;
    sw[lane + 128] = w2;  og[lane + 128] = w2;
    if (tail) { sw[lane + 192] = w3; og[lane + 192] = w3; }
  }
  __syncthreads();  // weights visible; skh dead -> reuse for partials

  // ---- epilogue: wave (qg,kg) partial GEMV over its k-range ----
  {
    float* pk = skh;  // [16][4][64] partials
    const int kstart = 52 * kg;
    const int kend = (kg == 3) ? kNK : (kstart + 52);
    const float* kb2 = kb + lane;  // d = lane
    float acc[4] = {0.f, 0.f, 0.f, 0.f};
    for (int k0 = kstart; k0 < kend; k0 += 4) {
      const float kv0 = kb2[(size_t)(k0 + 0) * kDK];
      const float kv1 = kb2[(size_t)(k0 + 1) * kDK];
      const float kv2 = kb2[(size_t)(k0 + 2) * kDK];
      const float kv3 = kb2[(size_t)(k0 + 3) * kDK];
#pragma unroll
      for (int qi = 0; qi < 4; ++qi) {
        const float4 wq = *reinterpret_cast<const float4*>(&ssc[(4 * qg + qi) * kNK + k0]);
        acc[qi] = fmaf(wq.x, kv0, acc[qi]);
        acc[qi] = fmaf(wq.y, kv1, acc[qi]);
        acc[qi] = fmaf(wq.z, kv2, acc[qi]);
        acc[qi] = fmaf(wq.w, kv3, acc[qi]);
      }
    }
#pragma unroll
    for (int qi = 0; qi < 4; ++qi)
      pk[((4 * qg + qi) * 4 + kg) * kDK + lane] = acc[qi];
  }
  __syncthreads();

  // ---- final combine: wave w sums 4 partials of query w ----
  {
    const float* pk = skh;
    const float r = pk[(wave * 4 + 0) * kDK + lane] + pk[(wave * 4 + 1) * kDK + lane] +
                    pk[(wave * 4 + 2) * kDK + lane] + pk[(wave * 4 + 3) * kDK + lane];
    out_attn[((size_t)b * kNQ + wave) * kDK + lane] = r;
  }
}

}  // namespace

extern "C" void kernel_launch(void* const* d_in, const int* in_sizes, int n_in,
                              void* d_out, int out_size, void* d_ws, size_t ws_size,
                              hipStream_t stream) {
  const float* queries = (const float*)d_in[0];
  const float* keys    = (const float*)d_in[1];
  const float* masks   = (const float*)d_in[2];
  // d_in[3] = num_neg (unused)
  const float* Wq = (const float*)d_in[4];
  const float* bq = (const float*)d_in[5];
  const float* Wk = (const float*)d_in[6];
  const float* bk = (const float*)d_in[7];
  const float* Wv = (const float*)d_in[8];
  // d_in[9] = bv: softmax-invariant, dropped

  float* out_attn = (float*)d_out;                       // (B, NQ, 64)
  float* out_w    = out_attn + (size_t)kNB * kNQ * kDK;  // (B, NQ, 200, 1)

  hipFuncSetAttribute((const void*)bahdanau_fused,
                      hipFuncAttributeMaxDynamicSharedMemorySize, (int)kSmemBytes);

  bahdanau_fused<<<kNB, kThreads, kSmemBytes, stream>>>(queries, keys, masks, Wq, bq,
                                                        Wk, bk, Wv, out_attn, out_w);
}

// Round 5
// 47.357 us; speedup vs baseline: 1.2810x; 1.0936x over previous
//
#include <hip/hip_runtime.h>

namespace {

typedef __attribute__((ext_vector_type(8))) short short8;  // 8 bf16 = 4 VGPR
typedef __attribute__((ext_vector_type(4))) float f32x4;   // MFMA accumulator

constexpr int kNB = 256;   // batch
constexpr int kNQ = 16;    // queries per batch
constexpr int kNK = 200;   // keys per batch
constexpr int kDK = 64;    // key/query feature size
constexpr int kNH = 128;   // hidden
constexpr int kThreads = 1024;  // 16 waves
constexpr int kS = 132;         // kh row stride in floats
constexpr float kNeg = -1000000000.0f;
constexpr float kC2 = 2.8853900817779268f;  // 2*log2(e): exp(2x)=exp2(kC2*x)

constexpr int kKhFloats = kNK * kS;   // 26400 floats = 105600 B
constexpr int kScFloats = kNQ * kNK;  // 3200 floats  = 12800 B
constexpr int kQhFloats = kNQ * kNH;  // 2048 floats  = 8192 B
constexpr size_t kSmemBytes =
    (size_t)(kKhFloats + kScFloats + kQhFloats) * sizeof(float);  // 126592 B

__device__ __forceinline__ float exp2_hw(float x) {
#if defined(__has_builtin)
# if __has_builtin(__builtin_amdgcn_exp2f)
  return __builtin_amdgcn_exp2f(x);
# else
  return __expf(x * 0.69314718055994531f);
# endif
#else
  return __expf(x * 0.69314718055994531f);
#endif
}

template <int CTRL>
__device__ __forceinline__ float dpp_add(float v) {
  int sw = __builtin_amdgcn_update_dpp(0, __float_as_int(v), CTRL, 0xF, 0xF, true);
  return v + __int_as_float(sw);
}

// ---- split-bf16 helpers (round-to-nearest-even) ----
__device__ __forceinline__ short bf_hi(float x) {
  unsigned u = __float_as_uint(x);
  return (short)((u + 0x7FFFu + ((u >> 16) & 1u)) >> 16);
}
__device__ __forceinline__ float bf_f(short s) {
  return __uint_as_float(((unsigned)(unsigned short)s) << 16);
}
// 8 floats -> hi/lo bf16x8 fragments (k-order j=0..7)
__device__ __forceinline__ void split8(float4 a, float4 b, short8& hi, short8& lo) {
  float v[8] = {a.x, a.y, a.z, a.w, b.x, b.y, b.z, b.w};
#pragma unroll
  for (int j = 0; j < 8; ++j) {
    const short h = bf_hi(v[j]);
    hi[j] = h;
    lo[j] = bf_hi(v[j] - bf_f(h));
  }
}

// 16 waves = 4 waves/SIMD -> <=128 VGPR budget.
__launch_bounds__(kThreads, 4)
__global__ void bahdanau_fused(const float* __restrict__ queries,
                               const float* __restrict__ keys,
                               const float* __restrict__ masks,
                               const float* __restrict__ Wq,
                               const float* __restrict__ bq,
                               const float* __restrict__ Wk,
                               const float* __restrict__ bk,
                               const float* __restrict__ Wv,
                               float* __restrict__ out_attn,
                               float* __restrict__ out_w) {
  extern __shared__ __align__(16) float smem[];
  float* skh = smem;                           // [200][132] kh' (later: partials)
  float* ssc = smem + kKhFloats;               // [16][200] scores -> weights
  float* sqh = smem + kKhFloats + kScFloats;   // [16][128] qh'

  const int tid  = threadIdx.x;
  const int b    = blockIdx.x;
  const int lane = tid & 63;
  const int wave = __builtin_amdgcn_readfirstlane(tid >> 6);   // 0..15
  const int l15  = lane & 15;
  const int q16  = lane >> 4;
  const int hbase = 8 * l15;

  const float* kb = keys + (size_t)b * kNK * kDK;
  const float* qb = queries + (size_t)b * kNQ * kDK;

  // ================== projections on the matrix pipe ==================
  // kh(200x128) = keys(200x64) @ Wk(64x128); qh(16x128) = queries @ Wq.
  // Wave w owns col-tile tc=w>>1 (cols tc*16..+15). Even w: row-tiles 0..6,
  // odd w: row-tiles 7..12 plus the query tile. Split-bf16 3-product for
  // f32-grade accuracy: D += ah*bh + ah*bl + al*bh  (al*bl term ~2^-18).
  {
    const int tc  = wave >> 1;
    const int odd = wave & 1;
    const int col = tc * 16 + l15;
    const int kj0 = q16 * 8;             // this lane's k-base within a kpart

    // B fragments (Wk col-slice), once per wave
    short8 bh[2], bl[2];
#pragma unroll
    for (int p = 0; p < 2; ++p) {
      float4 v0, v1;
      v0.x = Wk[(p * 32 + kj0 + 0) * kNH + col];
      v0.y = Wk[(p * 32 + kj0 + 1) * kNH + col];
      v0.z = Wk[(p * 32 + kj0 + 2) * kNH + col];
      v0.w = Wk[(p * 32 + kj0 + 3) * kNH + col];
      v1.x = Wk[(p * 32 + kj0 + 4) * kNH + col];
      v1.y = Wk[(p * 32 + kj0 + 5) * kNH + col];
      v1.z = Wk[(p * 32 + kj0 + 6) * kNH + col];
      v1.w = Wk[(p * 32 + kj0 + 7) * kNH + col];
      split8(v0, v1, bh[p], bl[p]);
    }
    const float bkc = bk[col];

    const int trB = odd ? 7 : 0;
    const int trE = odd ? 13 : 7;  // [trB, trE)
    for (int tr = trB; tr < trE; ++tr) {
      f32x4 acc = {0.f, 0.f, 0.f, 0.f};
      const int row = tr * 16 + l15;
      const bool ok = row < kNK;  // pad rows 200..207 of tile 12
#pragma unroll
      for (int p = 0; p < 2; ++p) {
        float4 a0 = {0.f, 0.f, 0.f, 0.f}, a1 = {0.f, 0.f, 0.f, 0.f};
        if (ok) {
          const float* ap = kb + (size_t)row * kDK + p * 32 + kj0;
          a0 = *reinterpret_cast<const float4*>(ap);
          a1 = *reinterpret_cast<const float4*>(ap + 4);
        }
        short8 ah, al;
        split8(a0, a1, ah, al);
        acc = __builtin_amdgcn_mfma_f32_16x16x32_bf16(al, bh[p], acc, 0, 0, 0);
        acc = __builtin_amdgcn_mfma_f32_16x16x32_bf16(ah, bl[p], acc, 0, 0, 0);
        acc = __builtin_amdgcn_mfma_f32_16x16x32_bf16(ah, bh[p], acc, 0, 0, 0);
      }
#pragma unroll
      for (int r = 0; r < 4; ++r) {
        const int rr = tr * 16 + q16 * 4 + r;  // C row = (lane>>4)*4 + reg
        if (rr < kNK) skh[(size_t)rr * kS + col] = kC2 * (acc[r] + bkc);
      }
    }

    if (odd) {  // query tile: rows 0..15
      short8 qbh[2], qbl[2];
#pragma unroll
      for (int p = 0; p < 2; ++p) {
        float4 v0, v1;
        v0.x = Wq[(p * 32 + kj0 + 0) * kNH + col];
        v0.y = Wq[(p * 32 + kj0 + 1) * kNH + col];
        v0.z = Wq[(p * 32 + kj0 + 2) * kNH + col];
        v0.w = Wq[(p * 32 + kj0 + 3) * kNH + col];
        v1.x = Wq[(p * 32 + kj0 + 4) * kNH + col];
        v1.y = Wq[(p * 32 + kj0 + 5) * kNH + col];
        v1.z = Wq[(p * 32 + kj0 + 6) * kNH + col];
        v1.w = Wq[(p * 32 + kj0 + 7) * kNH + col];
        split8(v0, v1, qbh[p], qbl[p]);
      }
      const float bqc = bq[col];
      f32x4 acc = {0.f, 0.f, 0.f, 0.f};
#pragma unroll
      for (int p = 0; p < 2; ++p) {
        const float* ap = qb + (size_t)l15 * kDK + p * 32 + kj0;
        const float4 a0 = *reinterpret_cast<const float4*>(ap);
        const float4 a1 = *reinterpret_cast<const float4*>(ap + 4);
        short8 ah, al;
        split8(a0, a1, ah, al);
        acc = __builtin_amdgcn_mfma_f32_16x16x32_bf16(al, qbh[p], acc, 0, 0, 0);
        acc = __builtin_amdgcn_mfma_f32_16x16x32_bf16(ah, qbl[p], acc, 0, 0, 0);
        acc = __builtin_amdgcn_mfma_f32_16x16x32_bf16(ah, qbh[p], acc, 0, 0, 0);
      }
#pragma unroll
      for (int r = 0; r < 4; ++r)
        sqh[(size_t)(q16 * 4 + r) * kNH + col] = kC2 * (acc[r] + bqc);
    }
  }

  // per-lane Wv slice
  float wv2[8];
  {
    const float4 wva = *reinterpret_cast<const float4*>(&Wv[hbase]);
    const float4 wvb = *reinterpret_cast<const float4*>(&Wv[hbase + 4]);
    wv2[0] = -2.0f * wva.x; wv2[1] = -2.0f * wva.y;
    wv2[2] = -2.0f * wva.z; wv2[3] = -2.0f * wva.w;
    wv2[4] = -2.0f * wvb.x; wv2[5] = -2.0f * wvb.y;
    wv2[6] = -2.0f * wvb.z; wv2[7] = -2.0f * wvb.w;
  }

  __syncthreads();  // qh' + kh' visible

  // ---- per-lane qh' slices: wave (qg,kg) covers queries 4qg..4qg+3, k-group kg ----
  const int qg = wave >> 2;
  const int kg = wave & 3;
  float qreg[4][8];
#pragma unroll
  for (int qi = 0; qi < 4; ++qi) {
    const float4 qa  = *reinterpret_cast<const float4*>(&sqh[(4 * qg + qi) * kNH + hbase]);
    const float4 qb4 = *reinterpret_cast<const float4*>(&sqh[(4 * qg + qi) * kNH + hbase + 4]);
    qreg[qi][0] = qa.x;  qreg[qi][1] = qa.y;  qreg[qi][2] = qa.z;  qreg[qi][3] = qa.w;
    qreg[qi][4] = qb4.x; qreg[qi][5] = qb4.y; qreg[qi][6] = qb4.z; qreg[qi][7] = qb4.w;
  }

  // ---- score: one kh read feeds 4 queries; k = 16i + 4kg + q16 ----
  {
    auto score_k = [&](int k) {
      const float* krow = &skh[(size_t)k * kS + hbase];
      const float4 ka  = *reinterpret_cast<const float4*>(krow);
      const float4 kb4 = *reinterpret_cast<const float4*>(krow + 4);
#pragma unroll
      for (int qi = 0; qi < 4; ++qi) {
        const float e0 = exp2_hw(qreg[qi][0] + ka.x);
        const float e1 = exp2_hw(qreg[qi][1] + ka.y);
        const float e2 = exp2_hw(qreg[qi][2] + ka.z);
        const float e3 = exp2_hw(qreg[qi][3] + ka.w);
        const float e4 = exp2_hw(qreg[qi][4] + kb4.x);
        const float e5 = exp2_hw(qreg[qi][5] + kb4.y);
        const float e6 = exp2_hw(qreg[qi][6] + kb4.z);
        const float e7 = exp2_hw(qreg[qi][7] + kb4.w);
        const float r0 = __builtin_amdgcn_rcpf(1.0f + e0);
        const float r1 = __builtin_amdgcn_rcpf(1.0f + e1);
        const float r2 = __builtin_amdgcn_rcpf(1.0f + e2);
        const float r3 = __builtin_amdgcn_rcpf(1.0f + e3);
        const float r4 = __builtin_amdgcn_rcpf(1.0f + e4);
        const float r5 = __builtin_amdgcn_rcpf(1.0f + e5);
        const float r6 = __builtin_amdgcn_rcpf(1.0f + e6);
        const float r7 = __builtin_amdgcn_rcpf(1.0f + e7);
        float acc0 = wv2[0] * r0;
        acc0 = fmaf(wv2[1], r1, acc0);
        acc0 = fmaf(wv2[2], r2, acc0);
        acc0 = fmaf(wv2[3], r3, acc0);
        float acc1 = wv2[4] * r4;
        acc1 = fmaf(wv2[5], r5, acc1);
        acc1 = fmaf(wv2[6], r6, acc1);
        acc1 = fmaf(wv2[7], r7, acc1);
        float acc = acc0 + acc1;
        acc = dpp_add<0xB1>(acc);   // xor 1
        acc = dpp_add<0x4E>(acc);   // xor 2
        acc = dpp_add<0x141>(acc);  // row_half_mirror (8-fold)
        acc = dpp_add<0x140>(acc);  // row_mirror (16-fold)
        if (l15 == 0) ssc[(4 * qg + qi) * kNK + k] = acc;
      }
    };
    for (int i = 0; i < 12; ++i) score_k(16 * i + 4 * kg + q16);
    if (kg < 2) score_k(192 + 4 * kg + q16);  // tail k=192..199
  }

  // ---- mask prefetch ----
  const float* mrow = masks + ((size_t)b * kNQ + wave) * kNK;
  const bool tail = lane < (kNK - 192);
  const float mm0 = mrow[lane];
  const float mm1 = mrow[lane + 64];
  const float mm2 = mrow[lane + 128];
  const float mm3 = tail ? mrow[lane + 192] : 0.0f;

  __syncthreads();  // scores visible

  // ---- softmax over k (wave w owns query row w) ----
  {
    const float* sr = &ssc[wave * kNK];
    float v0 = fmaf(mm0, kNeg, sr[lane]);
    float v1 = fmaf(mm1, kNeg, sr[lane + 64]);
    float v2 = fmaf(mm2, kNeg, sr[lane + 128]);
    float v3 = tail ? fmaf(mm3, kNeg, sr[lane + 192]) : -1e30f;
    float m = fmaxf(fmaxf(v0, v1), fmaxf(v2, v3));
#pragma unroll
    for (int off = 32; off > 0; off >>= 1) m = fmaxf(m, __shfl_xor(m, off, 64));
    const float e0 = __expf(v0 - m);
    const float e1 = __expf(v1 - m);
    const float e2 = __expf(v2 - m);
    const float e3 = tail ? __expf(v3 - m) : 0.f;
    float sum = (e0 + e1) + (e2 + e3);
#pragma unroll
    for (int off = 32; off > 0; off >>= 1) sum += __shfl_xor(sum, off, 64);
    const float rs = __builtin_amdgcn_rcpf(sum);
    float* og = out_w + ((size_t)b * kNQ + wave) * kNK;
    float* sw = &ssc[wave * kNK];
    const float w0 = e0 * rs, w1 = e1 * rs, w2 = e2 * rs, w3 = e3 * rs;
    sw[lane]       = w0;  og[lane]       = w0;
    sw[lane + 64]  = w1;  og[lane + 64]  = w1;
    sw[lane + 128] = w2;  og[lane + 128] = w2;
    if (tail) { sw[lane + 192] = w3; og[lane + 192] = w3; }
  }
  __syncthreads();  // weights visible; skh dead -> reuse for partials

  // ---- epilogue: wave (qg,kg) partial GEMV over its k-range ----
  {
    float* pk = skh;  // [16][4][64] partials
    const int kstart = 52 * kg;
    const int kend = (kg == 3) ? kNK : (kstart + 52);
    const float* kb2 = kb + lane;  // d = lane
    float acc[4] = {0.f, 0.f, 0.f, 0.f};
    for (int k0 = kstart; k0 < kend; k0 += 4) {
      const float kv0 = kb2[(size_t)(k0 + 0) * kDK];
      const float kv1 = kb2[(size_t)(k0 + 1) * kDK];
      const float kv2 = kb2[(size_t)(k0 + 2) * kDK];
      const float kv3 = kb2[(size_t)(k0 + 3) * kDK];
#pragma unroll
      for (int qi = 0; qi < 4; ++qi) {
        const float4 wq = *reinterpret_cast<const float4*>(&ssc[(4 * qg + qi) * kNK + k0]);
        acc[qi] = fmaf(wq.x, kv0, acc[qi]);
        acc[qi] = fmaf(wq.y, kv1, acc[qi]);
        acc[qi] = fmaf(wq.z, kv2, acc[qi]);
        acc[qi] = fmaf(wq.w, kv3, acc[qi]);
      }
    }
#pragma unroll
    for (int qi = 0; qi < 4; ++qi)
      pk[((4 * qg + qi) * 4 + kg) * kDK + lane] = acc[qi];
  }
  __syncthreads();

  // ---- final combine: wave w sums 4 partials of query w ----
  {
    const float* pk = skh;
    const float r = pk[(wave * 4 + 0) * kDK + lane] + pk[(wave * 4 + 1) * kDK + lane] +
                    pk[(wave * 4 + 2) * kDK + lane] + pk[(wave * 4 + 3) * kDK + lane];
    out_attn[((size_t)b * kNQ + wave) * kDK + lane] = r;
  }
}

}  // namespace

extern "C" void kernel_launch(void* const* d_in, const int* in_sizes, int n_in,
                              void* d_out, int out_size, void* d_ws, size_t ws_size,
                              hipStream_t stream) {
  const float* queries = (const float*)d_in[0];
  const float* keys    = (const float*)d_in[1];
  const float* masks   = (const float*)d_in[2];
  // d_in[3] = num_neg (unused)
  const float* Wq = (const float*)d_in[4];
  const float* bq = (const float*)d_in[5];
  const float* Wk = (const float*)d_in[6];
  const float* bk = (const float*)d_in[7];
  const float* Wv = (const float*)d_in[8];
  // d_in[9] = bv: softmax-invariant, dropped

  float* out_attn = (float*)d_out;                       // (B, NQ, 64)
  float* out_w    = out_attn + (size_t)kNB * kNQ * kDK;  // (B, NQ, 200, 1)

  hipFuncSetAttribute((const void*)bahdanau_fused,
                      hipFuncAttributeMaxDynamicSharedMemorySize, (int)kSmemBytes);

  bahdanau_fused<<<kNB, kThreads, kSmemBytes, stream>>>(queries, keys, masks, Wq, bq,
                                                        Wk, bk, Wv, out_attn, out_w);
}

// Round 6
// 38.402 us; speedup vs baseline: 1.5797x; 1.2332x over previous
//
#include <hip/hip_runtime.h>

namespace {

typedef __attribute__((ext_vector_type(8))) short short8;  // 8 bf16 = 4 VGPR
typedef __attribute__((ext_vector_type(4))) float f32x4;   // MFMA accumulator

constexpr int kNB = 256;   // batch
constexpr int kNQ = 16;    // queries per batch
constexpr int kNK = 200;   // keys per batch
constexpr int kDK = 64;    // key/query feature size
constexpr int kNH = 128;   // hidden
constexpr int kThreads = 1024;  // 16 waves
constexpr int kS = 132;         // Ek row stride in floats
constexpr float kNeg = -1000000000.0f;
constexpr float kC2 = 2.8853900817779268f;  // 2*log2(e): exp(2x)=exp2(kC2*x)

constexpr int kKhFloats = kNK * kS;   // 26400 floats = 105600 B
constexpr int kScFloats = kNQ * kNK;  // 3200 floats  = 12800 B
constexpr int kQhFloats = kNQ * kNH;  // 2048 floats  = 8192 B
constexpr size_t kSmemBytes =
    (size_t)(kKhFloats + kScFloats + kQhFloats) * sizeof(float);  // 126592 B

__device__ __forceinline__ float exp2_hw(float x) {
#if defined(__has_builtin)
# if __has_builtin(__builtin_amdgcn_exp2f)
  return __builtin_amdgcn_exp2f(x);
# else
  return __expf(x * 0.69314718055994531f);
# endif
#else
  return __expf(x * 0.69314718055994531f);
#endif
}

template <int CTRL>
__device__ __forceinline__ float dpp_add(float v) {
  int sw = __builtin_amdgcn_update_dpp(0, __float_as_int(v), CTRL, 0xF, 0xF, true);
  return v + __int_as_float(sw);
}

// ---- split-bf16 helpers (round-to-nearest-even) ----
__device__ __forceinline__ short bf_hi(float x) {
  unsigned u = __float_as_uint(x);
  return (short)((u + 0x7FFFu + ((u >> 16) & 1u)) >> 16);
}
__device__ __forceinline__ float bf_f(short s) {
  return __uint_as_float(((unsigned)(unsigned short)s) << 16);
}
__device__ __forceinline__ void split8(float4 a, float4 b, short8& hi, short8& lo) {
  float v[8] = {a.x, a.y, a.z, a.w, b.x, b.y, b.z, b.w};
#pragma unroll
  for (int j = 0; j < 8; ++j) {
    const short h = bf_hi(v[j]);
    hi[j] = h;
    lo[j] = bf_hi(v[j] - bf_f(h));
  }
}

// 126KB LDS pins us to 1 block/CU = 4 waves/SIMD; clamp the allocator's
// occupancy target to exactly that so it stops squeezing VGPRs to 32
// (R5 pathology: qreg/wv2 re-read from LDS every score iteration).
__launch_bounds__(kThreads)
__attribute__((amdgpu_waves_per_eu(4, 4)))
__global__ void bahdanau_fused(const float* __restrict__ queries,
                               const float* __restrict__ keys,
                               const float* __restrict__ masks,
                               const float* __restrict__ Wq,
                               const float* __restrict__ bq,
                               const float* __restrict__ Wk,
                               const float* __restrict__ bk,
                               const float* __restrict__ Wv,
                               float* __restrict__ out_attn,
                               float* __restrict__ out_w) {
  extern __shared__ __align__(16) float smem[];
  float* skh = smem;                           // [200][132] Ek=exp2(kh') (later: partials)
  float* ssc = smem + kKhFloats;               // [16][200] scores -> weights
  float* sqh = smem + kKhFloats + kScFloats;   // [16][128] Eq=exp2(qh')

  const int tid  = threadIdx.x;
  const int b    = blockIdx.x;
  const int lane = tid & 63;
  const int wave = __builtin_amdgcn_readfirstlane(tid >> 6);   // 0..15
  const int l15  = lane & 15;
  const int q16  = lane >> 4;
  const int hbase = 8 * l15;

  const float* kb = keys + (size_t)b * kNK * kDK;
  const float* qb = queries + (size_t)b * kNQ * kDK;

  // ================== projections on the matrix pipe ==================
  // kh(200x128)=keys@Wk, qh(16x128)=queries@Wq via split-bf16 3-product MFMA
  // (error ~2^-18). Store Ek=exp2(kC2*kh), Eq=exp2(kC2*qh): the score loop
  // then needs only a mul + rcp per element (exp(q+k) = exp(q)*exp(k)).
  {
    const int tc  = wave >> 1;
    const int odd = wave & 1;
    const int col = tc * 16 + l15;
    const int kj0 = q16 * 8;             // this lane's k-base within a kpart

    short8 bh[2], bl[2];                 // Wk col-slice fragments, once per wave
#pragma unroll
    for (int p = 0; p < 2; ++p) {
      float4 v0, v1;
      v0.x = Wk[(p * 32 + kj0 + 0) * kNH + col];
      v0.y = Wk[(p * 32 + kj0 + 1) * kNH + col];
      v0.z = Wk[(p * 32 + kj0 + 2) * kNH + col];
      v0.w = Wk[(p * 32 + kj0 + 3) * kNH + col];
      v1.x = Wk[(p * 32 + kj0 + 4) * kNH + col];
      v1.y = Wk[(p * 32 + kj0 + 5) * kNH + col];
      v1.z = Wk[(p * 32 + kj0 + 6) * kNH + col];
      v1.w = Wk[(p * 32 + kj0 + 7) * kNH + col];
      split8(v0, v1, bh[p], bl[p]);
    }
    const float bkc = bk[col];

    const int trB = odd ? 7 : 0;
    const int trE = odd ? 13 : 7;  // [trB, trE)
    for (int tr = trB; tr < trE; ++tr) {
      f32x4 acc = {0.f, 0.f, 0.f, 0.f};
      const int row = tr * 16 + l15;
      const bool ok = row < kNK;  // pad rows 200..207 of tile 12
#pragma unroll
      for (int p = 0; p < 2; ++p) {
        float4 a0 = {0.f, 0.f, 0.f, 0.f}, a1 = {0.f, 0.f, 0.f, 0.f};
        if (ok) {
          const float* ap = kb + (size_t)row * kDK + p * 32 + kj0;
          a0 = *reinterpret_cast<const float4*>(ap);
          a1 = *reinterpret_cast<const float4*>(ap + 4);
        }
        short8 ah, al;
        split8(a0, a1, ah, al);
        acc = __builtin_amdgcn_mfma_f32_16x16x32_bf16(al, bh[p], acc, 0, 0, 0);
        acc = __builtin_amdgcn_mfma_f32_16x16x32_bf16(ah, bl[p], acc, 0, 0, 0);
        acc = __builtin_amdgcn_mfma_f32_16x16x32_bf16(ah, bh[p], acc, 0, 0, 0);
      }
#pragma unroll
      for (int r = 0; r < 4; ++r) {
        const int rr = tr * 16 + q16 * 4 + r;  // C row = (lane>>4)*4 + reg
        if (rr < kNK) skh[(size_t)rr * kS + col] = exp2_hw(kC2 * (acc[r] + bkc));
      }
    }

    if (odd) {  // query tile: rows 0..15
      short8 qbh[2], qbl[2];
#pragma unroll
      for (int p = 0; p < 2; ++p) {
        float4 v0, v1;
        v0.x = Wq[(p * 32 + kj0 + 0) * kNH + col];
        v0.y = Wq[(p * 32 + kj0 + 1) * kNH + col];
        v0.z = Wq[(p * 32 + kj0 + 2) * kNH + col];
        v0.w = Wq[(p * 32 + kj0 + 3) * kNH + col];
        v1.x = Wq[(p * 32 + kj0 + 4) * kNH + col];
        v1.y = Wq[(p * 32 + kj0 + 5) * kNH + col];
        v1.z = Wq[(p * 32 + kj0 + 6) * kNH + col];
        v1.w = Wq[(p * 32 + kj0 + 7) * kNH + col];
        split8(v0, v1, qbh[p], qbl[p]);
      }
      const float bqc = bq[col];
      f32x4 acc = {0.f, 0.f, 0.f, 0.f};
#pragma unroll
      for (int p = 0; p < 2; ++p) {
        const float* ap = qb + (size_t)l15 * kDK + p * 32 + kj0;
        const float4 a0 = *reinterpret_cast<const float4*>(ap);
        const float4 a1 = *reinterpret_cast<const float4*>(ap + 4);
        short8 ah, al;
        split8(a0, a1, ah, al);
        acc = __builtin_amdgcn_mfma_f32_16x16x32_bf16(al, qbh[p], acc, 0, 0, 0);
        acc = __builtin_amdgcn_mfma_f32_16x16x32_bf16(ah, qbl[p], acc, 0, 0, 0);
        acc = __builtin_amdgcn_mfma_f32_16x16x32_bf16(ah, qbh[p], acc, 0, 0, 0);
      }
#pragma unroll
      for (int r = 0; r < 4; ++r)
        sqh[(size_t)(q16 * 4 + r) * kNH + col] = exp2_hw(kC2 * (acc[r] + bqc));
    }
  }

  // per-lane Wv slice
  float wv2[8];
  {
    const float4 wva = *reinterpret_cast<const float4*>(&Wv[hbase]);
    const float4 wvb = *reinterpret_cast<const float4*>(&Wv[hbase + 4]);
    wv2[0] = -2.0f * wva.x; wv2[1] = -2.0f * wva.y;
    wv2[2] = -2.0f * wva.z; wv2[3] = -2.0f * wva.w;
    wv2[4] = -2.0f * wvb.x; wv2[5] = -2.0f * wvb.y;
    wv2[6] = -2.0f * wvb.z; wv2[7] = -2.0f * wvb.w;
  }

  __syncthreads();  // Eq + Ek visible

  // ---- per-lane Eq slices: wave (qg,kg) covers queries 4qg..4qg+3, k-group kg ----
  const int qg = wave >> 2;
  const int kg = wave & 3;
  float qreg[4][8];
#pragma unroll
  for (int qi = 0; qi < 4; ++qi) {
    const float4 qa  = *reinterpret_cast<const float4*>(&sqh[(4 * qg + qi) * kNH + hbase]);
    const float4 qb4 = *reinterpret_cast<const float4*>(&sqh[(4 * qg + qi) * kNH + hbase + 4]);
    qreg[qi][0] = qa.x;  qreg[qi][1] = qa.y;  qreg[qi][2] = qa.z;  qreg[qi][3] = qa.w;
    qreg[qi][4] = qb4.x; qreg[qi][5] = qb4.y; qreg[qi][6] = qb4.z; qreg[qi][7] = qb4.w;
  }
#pragma unroll
  for (int qi = 0; qi < 4; ++qi)
#pragma unroll
    for (int m = 0; m < 8; ++m) asm volatile("" : "+v"(qreg[qi][m]));  // keep resident

  // ---- score: tanh(x) = 1 - 2*rcp(1 + Eq*Ek); constant 1s drop in softmax ----
  {
    auto score_k = [&](int k) {
      const float* krow = &skh[(size_t)k * kS + hbase];
      const float4 ka  = *reinterpret_cast<const float4*>(krow);
      const float4 kb4 = *reinterpret_cast<const float4*>(krow + 4);
#pragma unroll
      for (int qi = 0; qi < 4; ++qi) {
        const float e0 = qreg[qi][0] * ka.x;
        const float e1 = qreg[qi][1] * ka.y;
        const float e2 = qreg[qi][2] * ka.z;
        const float e3 = qreg[qi][3] * ka.w;
        const float e4 = qreg[qi][4] * kb4.x;
        const float e5 = qreg[qi][5] * kb4.y;
        const float e6 = qreg[qi][6] * kb4.z;
        const float e7 = qreg[qi][7] * kb4.w;
        const float r0 = __builtin_amdgcn_rcpf(1.0f + e0);
        const float r1 = __builtin_amdgcn_rcpf(1.0f + e1);
        const float r2 = __builtin_amdgcn_rcpf(1.0f + e2);
        const float r3 = __builtin_amdgcn_rcpf(1.0f + e3);
        const float r4 = __builtin_amdgcn_rcpf(1.0f + e4);
        const float r5 = __builtin_amdgcn_rcpf(1.0f + e5);
        const float r6 = __builtin_amdgcn_rcpf(1.0f + e6);
        const float r7 = __builtin_amdgcn_rcpf(1.0f + e7);
        float acc0 = wv2[0] * r0;
        acc0 = fmaf(wv2[1], r1, acc0);
        acc0 = fmaf(wv2[2], r2, acc0);
        acc0 = fmaf(wv2[3], r3, acc0);
        float acc1 = wv2[4] * r4;
        acc1 = fmaf(wv2[5], r5, acc1);
        acc1 = fmaf(wv2[6], r6, acc1);
        acc1 = fmaf(wv2[7], r7, acc1);
        float acc = acc0 + acc1;
        acc = dpp_add<0xB1>(acc);   // xor 1
        acc = dpp_add<0x4E>(acc);   // xor 2
        acc = dpp_add<0x141>(acc);  // row_half_mirror (8-fold)
        acc = dpp_add<0x140>(acc);  // row_mirror (16-fold)
        if (l15 == 0) ssc[(4 * qg + qi) * kNK + k] = acc;
      }
    };
    for (int i = 0; i < 12; ++i) score_k(16 * i + 4 * kg + q16);
    if (kg < 2) score_k(192 + 4 * kg + q16);  // tail k=192..199
  }

  // ---- mask prefetch ----
  const float* mrow = masks + ((size_t)b * kNQ + wave) * kNK;
  const bool tail = lane < (kNK - 192);
  const float mm0 = mrow[lane];
  const float mm1 = mrow[lane + 64];
  const float mm2 = mrow[lane + 128];
  const float mm3 = tail ? mrow[lane + 192] : 0.0f;

  __syncthreads();  // scores visible

  // ---- softmax over k (wave w owns query row w) ----
  {
    const float* sr = &ssc[wave * kNK];
    float v0 = fmaf(mm0, kNeg, sr[lane]);
    float v1 = fmaf(mm1, kNeg, sr[lane + 64]);
    float v2 = fmaf(mm2, kNeg, sr[lane + 128]);
    float v3 = tail ? fmaf(mm3, kNeg, sr[lane + 192]) : -1e30f;
    float m = fmaxf(fmaxf(v0, v1), fmaxf(v2, v3));
#pragma unroll
    for (int off = 32; off > 0; off >>= 1) m = fmaxf(m, __shfl_xor(m, off, 64));
    const float e0 = __expf(v0 - m);
    const float e1 = __expf(v1 - m);
    const float e2 = __expf(v2 - m);
    const float e3 = tail ? __expf(v3 - m) : 0.f;
    float sum = (e0 + e1) + (e2 + e3);
#pragma unroll
    for (int off = 32; off > 0; off >>= 1) sum += __shfl_xor(sum, off, 64);
    const float rs = __builtin_amdgcn_rcpf(sum);
    float* og = out_w + ((size_t)b * kNQ + wave) * kNK;
    float* sw = &ssc[wave * kNK];
    const float w0 = e0 * rs, w1 = e1 * rs, w2 = e2 * rs, w3 = e3 * rs;
    sw[lane]       = w0;  og[lane]       = w0;
    sw[lane + 64]  = w1;  og[lane + 64]  = w1;
    sw[lane + 128] = w2;  og[lane + 128] = w2;
    if (tail) { sw[lane + 192] = w3; og[lane + 192] = w3; }
  }
  __syncthreads();  // weights visible; skh dead -> reuse for partials

  // ---- epilogue: wave (qg,kg) partial GEMV over its k-range ----
  {
    float* pk = skh;  // [16][4][64] partials
    const int kstart = 52 * kg;
    const int kend = (kg == 3) ? kNK : (kstart + 52);
    const float* kb2 = kb + lane;  // d = lane
    float acc[4] = {0.f, 0.f, 0.f, 0.f};
    for (int k0 = kstart; k0 < kend; k0 += 4) {
      const float kv0 = kb2[(size_t)(k0 + 0) * kDK];
      const float kv1 = kb2[(size_t)(k0 + 1) * kDK];
      const float kv2 = kb2[(size_t)(k0 + 2) * kDK];
      const float kv3 = kb2[(size_t)(k0 + 3) * kDK];
#pragma unroll
      for (int qi = 0; qi < 4; ++qi) {
        const float4 wq = *reinterpret_cast<const float4*>(&ssc[(4 * qg + qi) * kNK + k0]);
        acc[qi] = fmaf(wq.x, kv0, acc[qi]);
        acc[qi] = fmaf(wq.y, kv1, acc[qi]);
        acc[qi] = fmaf(wq.z, kv2, acc[qi]);
        acc[qi] = fmaf(wq.w, kv3, acc[qi]);
      }
    }
#pragma unroll
    for (int qi = 0; qi < 4; ++qi)
      pk[((4 * qg + qi) * 4 + kg) * kDK + lane] = acc[qi];
  }
  __syncthreads();

  // ---- final combine: wave w sums 4 partials of query w ----
  {
    const float* pk = skh;
    const float r = pk[(wave * 4 + 0) * kDK + lane] + pk[(wave * 4 + 1) * kDK + lane] +
                    pk[(wave * 4 + 2) * kDK + lane] + pk[(wave * 4 + 3) * kDK + lane];
    out_attn[((size_t)b * kNQ + wave) * kDK + lane] = r;
  }
}

}  // namespace

extern "C" void kernel_launch(void* const* d_in, const int* in_sizes, int n_in,
                              void* d_out, int out_size, void* d_ws, size_t ws_size,
                              hipStream_t stream) {
  const float* queries = (const float*)d_in[0];
  const float* keys    = (const float*)d_in[1];
  const float* masks   = (const float*)d_in[2];
  // d_in[3] = num_neg (unused)
  const float* Wq = (const float*)d_in[4];
  const float* bq = (const float*)d_in[5];
  const float* Wk = (const float*)d_in[6];
  const float* bk = (const float*)d_in[7];
  const float* Wv = (const float*)d_in[8];
  // d_in[9] = bv: softmax-invariant, dropped

  float* out_attn = (float*)d_out;                       // (B, NQ, 64)
  float* out_w    = out_attn + (size_t)kNB * kNQ * kDK;  // (B, NQ, 200, 1)

  hipFuncSetAttribute((const void*)bahdanau_fused,
                      hipFuncAttributeMaxDynamicSharedMemorySize, (int)kSmemBytes);

  bahdanau_fused<<<kNB, kThreads, kSmemBytes, stream>>>(queries, keys, masks, Wq, bq,
                                                        Wk, bk, Wv, out_attn, out_w);
}